// Round 13
// baseline (192.811 us; speedup 1.0000x reference)
//
#include <hip/hip_runtime.h>

// B=2, N=64, D=256, H=8, DK=32.  ROWS = B*N*N = 8192.
#define ROWS 8192
#define DIM  256

typedef short short8 __attribute__((ext_vector_type(8)));
typedef float f4     __attribute__((ext_vector_type(4)));

__device__ __forceinline__ float bf2f(unsigned int u16) {
    union { unsigned int i; float f; } v;
    v.i = (u16 & 0xffffu) << 16;
    return v.f;
}
__device__ __forceinline__ unsigned short f2bf(float f) {
    union { float f; unsigned int u; } v; v.f = f;
    unsigned int r = v.u + 0x7fffu + ((v.u >> 16) & 1u);   // RNE
    return (unsigned short)(r >> 16);
}

// ---------------------------------------------------------------------------
// Merged casts. Blocks [0,2048): x(8192x256 fp32)->xb bf16.
// Blocks [2048,2624): weights -> WT[n][k] bf16 packed.
//   w0..w4 at w*65536 ; W1(256x512)->512x256 @327680 ; W2(512x256)->256x512 @458752
// ---------------------------------------------------------------------------
__global__ __launch_bounds__(256)
void cast_all(const float* __restrict__ x, unsigned short* __restrict__ xb,
              const float* __restrict__ w0, const float* __restrict__ w1,
              const float* __restrict__ w2, const float* __restrict__ w3,
              const float* __restrict__ w4, const float* __restrict__ w5,
              const float* __restrict__ w6, unsigned short* __restrict__ wt)
{
    if (blockIdx.x < 2048) {
        const size_t i = ((size_t)blockIdx.x * 256 + threadIdx.x) * 4;
        float4 v = *(const float4*)(x + i);
        uint2 p;
        p.x = f2bf(v.x) | ((unsigned int)f2bf(v.y) << 16);
        p.y = f2bf(v.z) | ((unsigned int)f2bf(v.w) << 16);
        *(uint2*)(xb + i) = p;
        return;
    }
    __shared__ float t[32][33];
    int id = blockIdx.x - 2048;
    const float* src; int K, N, Ntiles; size_t doff;
    if (id < 320) {
        int w = id >> 6; id &= 63; K = 256; N = 256; Ntiles = 8;
        doff = (size_t)w * 65536;
        src = (w == 0) ? w0 : (w == 1) ? w1 : (w == 2) ? w2 : (w == 3) ? w3 : w4;
    } else if (id < 448) {
        id -= 320; K = 256; N = 512; Ntiles = 16; doff = 327680; src = w5;
    } else {
        id -= 448; K = 512; N = 256; Ntiles = 8;  doff = 458752; src = w6;
    }
    const int tk = id / Ntiles, tn = id % Ntiles;
    const int k0 = tk * 32, n0 = tn * 32;
    const int c = threadIdx.x & 31, r8 = threadIdx.x >> 5;
    for (int rr = r8; rr < 32; rr += 8)
        t[rr][c] = src[(size_t)(k0 + rr) * N + n0 + c];
    __syncthreads();
    for (int rr = r8; rr < 32; rr += 8)
        wt[doff + (size_t)(n0 + rr) * K + k0 + c] = f2bf(t[c][rr]);
}

// ---------------------------------------------------------------------------
// Projection MFMA GEMM with head-major scatter epilogue (all-bf16 projT).
//   wsel 0 (lk): dst[b][h][x=i][a=j][d]   wsel 1 (rk): dst[b][h][a=i][y=j][d]
//   wsel 2 (lv): dst[b][h][x=i][a=j][d]   wsel 3 (rv): dst[b][h][y=j][a=i][d]
// grid = (16, 64)
// ---------------------------------------------------------------------------
__global__ __launch_bounds__(256)
void proj_mfma(const unsigned short* __restrict__ A, const unsigned short* __restrict__ WT,
               unsigned short* __restrict__ projT)
{
    const int lane = threadIdx.x & 63, wave = threadIdx.x >> 6;
    const int wsel = blockIdx.x >> 2;
    const int col0 = (blockIdx.x & 3) * 64;
    const int m0 = blockIdx.y * 128 + wave * 32;
    const int lm = lane & 15, lk8 = (lane >> 4) * 8;
    const unsigned short* W = WT + (size_t)wsel * 65536;
    unsigned short* dst = projT + (size_t)wsel * 2097152;

    f4 acc[2][4];
    #pragma unroll
    for (int i = 0; i < 2; ++i)
        #pragma unroll
        for (int j = 0; j < 4; ++j) acc[i][j] = (f4){0.f, 0.f, 0.f, 0.f};

    #pragma unroll 2
    for (int kc = 0; kc < 256; kc += 32) {
        short8 af[2], bf[4];
        #pragma unroll
        for (int i = 0; i < 2; ++i)
            af[i] = *(const short8*)(A + (size_t)(m0 + i * 16 + lm) * 256 + kc + lk8);
        #pragma unroll
        for (int j = 0; j < 4; ++j)
            bf[j] = *(const short8*)(W + (size_t)(col0 + j * 16 + lm) * 256 + kc + lk8);
        #pragma unroll
        for (int i = 0; i < 2; ++i)
            #pragma unroll
            for (int j = 0; j < 4; ++j)
                acc[i][j] = __builtin_amdgcn_mfma_f32_16x16x32_bf16(af[i], bf[j], acc[i][j], 0, 0, 0);
    }

    const int rbase = (lane >> 4) * 4;
    const int swap = (wsel == 3);
    #pragma unroll
    for (int i = 0; i < 2; ++i)
        #pragma unroll
        for (int j = 0; j < 4; ++j) {
            const int c = col0 + j * 16 + lm;
            const int h = c >> 5, d = c & 31;
            #pragma unroll
            for (int r = 0; r < 4; ++r) {
                const int m = m0 + i * 16 + rbase + r;
                const int b = m >> 12, ii = (m >> 6) & 63, jj = m & 63;
                const int p = swap ? jj : ii;
                const int q = swap ? ii : jj;
                const size_t idx = ((((size_t)b * 8 + h) * 64 + p) * 64 + q) * 32 + d;
                dst[idx] = f2bf(acc[i][j][r]);
            }
        }
}

// ---------------------------------------------------------------------------
// Scores via MFMA, occupancy-split: each (b,h,a) slice is TWO wave-tasks
// (mt-halves).  Wave slot s = (bi&31)*4 + wave in [0,128): a = s>>1,
// half = s&1 -> mt in {2*half, 2*half+1}.  grid = 512 (16 bh x 32), 256 thr.
// S[b][h][x][a][y] bf16.
// ---------------------------------------------------------------------------
__global__ __launch_bounds__(256)
void scores_mfma(const unsigned short* __restrict__ lkT, const unsigned short* __restrict__ rkT,
                 unsigned short* __restrict__ S)
{
    const int lane = threadIdx.x & 63, wave = threadIdx.x >> 6;
    const int bi = blockIdx.x;
    const size_t bh = bi >> 5;
    const int s = (bi & 31) * 4 + wave;
    const int a = s >> 1, half = s & 1;
    const int lm = lane & 15, lk8 = (lane >> 4) * 8;

    short8 af[2], bf[4];
    #pragma unroll
    for (int t = 0; t < 2; ++t)
        af[t] = *(const short8*)(lkT + ((bh * 64 + ((half * 2 + t) * 16 + lm)) * 64 + a) * 32 + lk8);
    #pragma unroll
    for (int t = 0; t < 4; ++t)
        bf[t] = *(const short8*)(rkT + ((bh * 64 + a) * 64 + (t * 16 + lm)) * 32 + lk8);

    const int rbase = (lane >> 4) * 4;
    unsigned short* Sb = S + bh * 262144 + a * 64;   // + x*4096 + y
    #pragma unroll
    for (int mt = 0; mt < 2; ++mt)
        #pragma unroll
        for (int nt = 0; nt < 4; ++nt) {
            f4 acc = (f4){0.f, 0.f, 0.f, 0.f};
            acc = __builtin_amdgcn_mfma_f32_16x16x32_bf16(af[mt], bf[nt], acc, 0, 0, 0);
            #pragma unroll
            for (int r = 0; r < 4; ++r) {
                const int xx = (half * 2 + mt) * 16 + rbase + r;
                const int yy = nt * 16 + lm;
                Sb[(size_t)xx * 4096 + yy] = f2bf(acc[r] * 0.17677669529663687f);
            }
        }
}

// ---------------------------------------------------------------------------
// Softmax over a + aggregation, block per (b,h,x), 256 thr.
// rv streamed bf16 (L2 stream 256MB agg — fp32 doubled it, +7us, r11).
// One-pass mapping: thread = (y = tid>>2, d-octet), single uint4 store.
// obuf[(b*64+x)*64+y][h*32+d] bf16.  grid = 1024.
// ---------------------------------------------------------------------------
__global__ __launch_bounds__(256)
void softmax_agg(const unsigned short* __restrict__ S, const unsigned short* __restrict__ lvT,
                 const unsigned short* __restrict__ rvT, unsigned short* __restrict__ obuf)
{
    __shared__ float att[64][64];           // [a][y]
    __shared__ float lvL[64][32];
    __shared__ float smx[4][64], ssm[4][64], invL[64];
    const int bi = blockIdx.x;
    const int b = bi >> 9, h = (bi >> 6) & 7, x = bi & 63;
    const size_t bh = (size_t)b * 8 + h;
    const int tid = threadIdx.x;

    {   // load S[x] slice (8KB bf16, contiguous) -> att f32 ; stage lv -> f32
        const int a = tid >> 2, yo = (tid & 3) * 16;
        const unsigned short* Sp = S + (bh * 64 + x) * 4096 + a * 64 + yo;
        uint4 p0 = *(const uint4*)(Sp);
        uint4 p1 = *(const uint4*)(Sp + 8);
        att[a][yo +  0] = bf2f(p0.x); att[a][yo +  1] = bf2f(p0.x >> 16);
        att[a][yo +  2] = bf2f(p0.y); att[a][yo +  3] = bf2f(p0.y >> 16);
        att[a][yo +  4] = bf2f(p0.z); att[a][yo +  5] = bf2f(p0.z >> 16);
        att[a][yo +  6] = bf2f(p0.w); att[a][yo +  7] = bf2f(p0.w >> 16);
        att[a][yo +  8] = bf2f(p1.x); att[a][yo +  9] = bf2f(p1.x >> 16);
        att[a][yo + 10] = bf2f(p1.y); att[a][yo + 11] = bf2f(p1.y >> 16);
        att[a][yo + 12] = bf2f(p1.z); att[a][yo + 13] = bf2f(p1.z >> 16);
        att[a][yo + 14] = bf2f(p1.w); att[a][yo + 15] = bf2f(p1.w >> 16);
        const int d0 = (tid & 3) * 8;
        uint4 q = *(const uint4*)(lvT + ((bh * 64 + x) * 64 + a) * 32 + d0);
        lvL[a][d0 + 0] = bf2f(q.x); lvL[a][d0 + 1] = bf2f(q.x >> 16);
        lvL[a][d0 + 2] = bf2f(q.y); lvL[a][d0 + 3] = bf2f(q.y >> 16);
        lvL[a][d0 + 4] = bf2f(q.z); lvL[a][d0 + 5] = bf2f(q.z >> 16);
        lvL[a][d0 + 6] = bf2f(q.w); lvL[a][d0 + 7] = bf2f(q.w >> 16);
    }
    __syncthreads();

    {   // per-slice max over a
        const int y = tid & 63, az = tid >> 6;
        float mx = -1e30f;
        for (int a = az; a < 64; a += 4) mx = fmaxf(mx, att[a][y]);
        smx[az][y] = mx;
    }
    __syncthreads();

    {   // exp + partial sums
        const int y = tid & 63, az = tid >> 6;
        const float mx = fmaxf(fmaxf(smx[0][y], smx[1][y]), fmaxf(smx[2][y], smx[3][y]));
        float s = 0.f;
        for (int a = az; a < 64; a += 4) {
            float e = __expf(att[a][y] - mx);
            att[a][y] = e;
            s += e;
        }
        ssm[az][y] = s;
    }
    __syncthreads();
    if (tid < 64)
        invL[tid] = 1.f / (ssm[0][tid] + ssm[1][tid] + ssm[2][tid] + ssm[3][tid]);
    __syncthreads();

    {   // aggregation: thread = (y = tid>>2, dq = tid&3), 8 d's each, one pass
        const int y = tid >> 2, d0 = (tid & 3) * 8;
        float o[8];
        #pragma unroll
        for (int i = 0; i < 8; ++i) o[i] = 0.f;
        const unsigned short* rvr = rvT + (bh * 64 + y) * 2048 + d0;
        #pragma unroll 8
        for (int a = 0; a < 64; ++a) {
            const float w = att[a][y];
            float4 lv0 = *(const float4*)&lvL[a][d0];
            float4 lv1 = *(const float4*)&lvL[a][d0 + 4];
            uint4 rv4 = *(const uint4*)(rvr + (size_t)a * 32);
            o[0] = fmaf(w * lv0.x, bf2f(rv4.x),       o[0]);
            o[1] = fmaf(w * lv0.y, bf2f(rv4.x >> 16), o[1]);
            o[2] = fmaf(w * lv0.z, bf2f(rv4.y),       o[2]);
            o[3] = fmaf(w * lv0.w, bf2f(rv4.y >> 16), o[3]);
            o[4] = fmaf(w * lv1.x, bf2f(rv4.z),       o[4]);
            o[5] = fmaf(w * lv1.y, bf2f(rv4.z >> 16), o[5]);
            o[6] = fmaf(w * lv1.z, bf2f(rv4.w),       o[6]);
            o[7] = fmaf(w * lv1.w, bf2f(rv4.w >> 16), o[7]);
        }
        const float inv = invL[y];
        uint4 pk;
        pk.x = f2bf(o[0] * inv) | ((unsigned int)f2bf(o[1] * inv) << 16);
        pk.y = f2bf(o[2] * inv) | ((unsigned int)f2bf(o[3] * inv) << 16);
        pk.z = f2bf(o[4] * inv) | ((unsigned int)f2bf(o[5] * inv) << 16);
        pk.w = f2bf(o[6] * inv) | ((unsigned int)f2bf(o[7] * inv) << 16);
        *(uint4*)(obuf + (((size_t)b * 64 + x) * 64 + y) * 256 + h * 32 + d0) = pk;
    }
}

// ---------------------------------------------------------------------------
// Fused GEMM + residual + LayerNorm (out-proj + LN1).
// tile: 16 rows x 256 cols; 4 waves, wave w covers cols w*64..+63.
// grid = 512, 256 thr.  resid fp32 (x), out bf16 (hb).
// ---------------------------------------------------------------------------
__global__ __launch_bounds__(256)
void gemm_ln1(const unsigned short* __restrict__ A, const unsigned short* __restrict__ WT,
              const float* __restrict__ resid,
              const float* __restrict__ gamma, const float* __restrict__ beta,
              unsigned short* __restrict__ out)
{
    constexpr int K = 256;
    __shared__ float ps[16][4], pq[16][4];
    const int lane = threadIdx.x & 63, wave = threadIdx.x >> 6;
    const int m0 = blockIdx.x * 16;
    const int col0 = wave * 64;
    const int lm = lane & 15, lk8 = (lane >> 4) * 8;

    f4 acc[4];
    #pragma unroll
    for (int j = 0; j < 4; ++j) acc[j] = (f4){0.f, 0.f, 0.f, 0.f};

    #pragma unroll 2
    for (int kc = 0; kc < K; kc += 32) {
        short8 af = *(const short8*)(A + (size_t)(m0 + lm) * K + kc + lk8);
        #pragma unroll
        for (int j = 0; j < 4; ++j) {
            short8 bf = *(const short8*)(WT + (size_t)(col0 + j * 16 + lm) * K + kc + lk8);
            acc[j] = __builtin_amdgcn_mfma_f32_16x16x32_bf16(af, bf, acc[j], 0, 0, 0);
        }
    }

    const int rbase = (lane >> 4) * 4;
    float v[4][4];
    float s[4] = {0.f, 0.f, 0.f, 0.f}, q[4] = {0.f, 0.f, 0.f, 0.f};
    #pragma unroll
    for (int j = 0; j < 4; ++j) {
        const int n = col0 + j * 16 + lm;
        #pragma unroll
        for (int r = 0; r < 4; ++r) {
            const int m = m0 + rbase + r;
            float t = acc[j][r] + resid[(size_t)m * 256 + n];
            v[j][r] = t;
            s[r] += t;
            q[r] = fmaf(t, t, q[r]);
        }
    }
    #pragma unroll
    for (int off = 1; off < 16; off <<= 1) {
        #pragma unroll
        for (int r = 0; r < 4; ++r) {
            s[r] += __shfl_xor(s[r], off);
            q[r] += __shfl_xor(q[r], off);
        }
    }
    if (lm == 0) {
        #pragma unroll
        for (int r = 0; r < 4; ++r) {
            ps[rbase + r][wave] = s[r];
            pq[rbase + r][wave] = q[r];
        }
    }
    __syncthreads();
    #pragma unroll
    for (int r = 0; r < 4; ++r) {
        const int lr = rbase + r;
        const float Sm = ps[lr][0] + ps[lr][1] + ps[lr][2] + ps[lr][3];
        const float Qm = pq[lr][0] + pq[lr][1] + pq[lr][2] + pq[lr][3];
        const float mu = Sm * (1.f / 256.f);
        const float ri = rsqrtf(Qm * (1.f / 256.f) - mu * mu + 1e-5f);
        const int m = m0 + lr;
        #pragma unroll
        for (int j = 0; j < 4; ++j) {
            const int n = col0 + j * 16 + lm;
            out[(size_t)m * 256 + n] = f2bf((v[j][r] - mu) * ri * gamma[n] + beta[n]);
        }
    }
}

// ---------------------------------------------------------------------------
// FFN1: out = relu( A(8192x256 bf16) @ WT(512x256)^T + bias ), bf16 out.
// tile 128x64 (wave = 32 rows x 64 cols) amortizes weight reads 8x better
// than 16-row blocks (r12 ffn_fused: 256MB L2 weight traffic, +2.5us).
// grid = (8, 64).
// ---------------------------------------------------------------------------
__global__ __launch_bounds__(256)
void gemm_ffn1(const unsigned short* __restrict__ A, const unsigned short* __restrict__ WT,
               const float* __restrict__ bias, unsigned short* __restrict__ outB)
{
    constexpr int K = 256, N = 512;
    const int lane = threadIdx.x & 63, wave = threadIdx.x >> 6;
    const int m0 = blockIdx.y * 128 + wave * 32;
    const int col0 = blockIdx.x * 64;
    const int lm = lane & 15, lk8 = (lane >> 4) * 8;

    f4 acc[2][4];
    #pragma unroll
    for (int i = 0; i < 2; ++i)
        #pragma unroll
        for (int j = 0; j < 4; ++j) acc[i][j] = (f4){0.f, 0.f, 0.f, 0.f};

    #pragma unroll 2
    for (int kc = 0; kc < K; kc += 32) {
        short8 af[2], bf[4];
        #pragma unroll
        for (int i = 0; i < 2; ++i)
            af[i] = *(const short8*)(A + (size_t)(m0 + i * 16 + lm) * K + kc + lk8);
        #pragma unroll
        for (int j = 0; j < 4; ++j)
            bf[j] = *(const short8*)(WT + (size_t)(col0 + j * 16 + lm) * K + kc + lk8);
        #pragma unroll
        for (int i = 0; i < 2; ++i)
            #pragma unroll
            for (int j = 0; j < 4; ++j)
                acc[i][j] = __builtin_amdgcn_mfma_f32_16x16x32_bf16(af[i], bf[j], acc[i][j], 0, 0, 0);
    }

    const int rbase = (lane >> 4) * 4;
    #pragma unroll
    for (int i = 0; i < 2; ++i)
        #pragma unroll
        for (int j = 0; j < 4; ++j) {
            const int n = col0 + j * 16 + lm;
            const float bb = bias[n];
            #pragma unroll
            for (int r = 0; r < 4; ++r) {
                const int m = m0 + i * 16 + rbase + r;
                outB[(size_t)m * N + n] = f2bf(fmaxf(acc[i][j][r] + bb, 0.f));
            }
        }
}

// ---------------------------------------------------------------------------
// FFN2 + residual(bf16 hb) + LN2 -> fp32 out.  K=512 compile-time.
// tile: 16 rows x 256 cols; 4 waves.  grid = 512, 256 thr.
// ---------------------------------------------------------------------------
__global__ __launch_bounds__(256)
void gemm_ln2(const unsigned short* __restrict__ A, const unsigned short* __restrict__ WT,
              const float* __restrict__ bias, const unsigned short* __restrict__ resid,
              const float* __restrict__ gamma, const float* __restrict__ beta,
              float* __restrict__ out)
{
    constexpr int K = 512;
    __shared__ float ps[16][4], pq[16][4];
    const int lane = threadIdx.x & 63, wave = threadIdx.x >> 6;
    const int m0 = blockIdx.x * 16;
    const int col0 = wave * 64;
    const int lm = lane & 15, lk8 = (lane >> 4) * 8;

    f4 acc[4];
    #pragma unroll
    for (int j = 0; j < 4; ++j) acc[j] = (f4){0.f, 0.f, 0.f, 0.f};

    #pragma unroll 2
    for (int kc = 0; kc < K; kc += 32) {
        short8 af = *(const short8*)(A + (size_t)(m0 + lm) * K + kc + lk8);
        #pragma unroll
        for (int j = 0; j < 4; ++j) {
            short8 bf = *(const short8*)(WT + (size_t)(col0 + j * 16 + lm) * K + kc + lk8);
            acc[j] = __builtin_amdgcn_mfma_f32_16x16x32_bf16(af, bf, acc[j], 0, 0, 0);
        }
    }

    const int rbase = (lane >> 4) * 4;
    float v[4][4];
    float s[4] = {0.f, 0.f, 0.f, 0.f}, q[4] = {0.f, 0.f, 0.f, 0.f};
    #pragma unroll
    for (int j = 0; j < 4; ++j) {
        const int n = col0 + j * 16 + lm;
        const float bb = bias[n];
        #pragma unroll
        for (int r = 0; r < 4; ++r) {
            const int m = m0 + rbase + r;
            float t = acc[j][r] + bb + bf2f(resid[(size_t)m * 256 + n]);
            v[j][r] = t;
            s[r] += t;
            q[r] = fmaf(t, t, q[r]);
        }
    }
    #pragma unroll
    for (int off = 1; off < 16; off <<= 1) {
        #pragma unroll
        for (int r = 0; r < 4; ++r) {
            s[r] += __shfl_xor(s[r], off);
            q[r] += __shfl_xor(q[r], off);
        }
    }
    if (lm == 0) {
        #pragma unroll
        for (int r = 0; r < 4; ++r) {
            ps[rbase + r][wave] = s[r];
            pq[rbase + r][wave] = q[r];
        }
    }
    __syncthreads();
    #pragma unroll
    for (int r = 0; r < 4; ++r) {
        const int lr = rbase + r;
        const float Sm = ps[lr][0] + ps[lr][1] + ps[lr][2] + ps[lr][3];
        const float Qm = pq[lr][0] + pq[lr][1] + pq[lr][2] + pq[lr][3];
        const float mu = Sm * (1.f / 256.f);
        const float ri = rsqrtf(Qm * (1.f / 256.f) - mu * mu + 1e-5f);
        const int m = m0 + lr;
        #pragma unroll
        for (int j = 0; j < 4; ++j) {
            const int n = col0 + j * 16 + lm;
            out[(size_t)m * 256 + n] = (v[j][r] - mu) * ri * gamma[n] + beta[n];
        }
    }
}

// ---------------------------------------------------------------------------
extern "C" void kernel_launch(void* const* d_in, const int* in_sizes, int n_in,
                              void* d_out, int out_size, void* d_ws, size_t ws_size,
                              hipStream_t stream)
{
    const float* x    = (const float*)d_in[0];
    const float* Wlk  = (const float*)d_in[1];
    const float* Wrk  = (const float*)d_in[2];
    const float* Wlv  = (const float*)d_in[3];
    const float* Wrv  = (const float*)d_in[4];
    const float* Wout = (const float*)d_in[5];
    const float* g1   = (const float*)d_in[6];
    const float* be1  = (const float*)d_in[7];
    const float* W1   = (const float*)d_in[8];
    const float* b1   = (const float*)d_in[9];
    const float* W2   = (const float*)d_in[10];
    const float* b2   = (const float*)d_in[11];
    const float* g2   = (const float*)d_in[12];
    const float* be2  = (const float*)d_in[13];

    char* base = (char*)d_ws;
    const size_t MB = 1ull << 20;
    unsigned short* xb    = (unsigned short*)(base + 0);        // 4MB; reused as obuf
    unsigned short* obufb = (unsigned short*)(base + 0);
    unsigned short* projT = (unsigned short*)(base + 4 * MB);   // lkT,rkT,lvT,rvT 4x4MB
    unsigned short* lkT   = projT;
    unsigned short* rkT   = projT + 2097152;
    unsigned short* lvT   = projT + 2 * 2097152;
    unsigned short* rvT   = projT + 3 * 2097152;
    unsigned short* hb    = (unsigned short*)(base + 20 * MB);  // 4MB bf16 h
    unsigned short* midb  = (unsigned short*)(base + 24 * MB);  // 8MB
    unsigned short* Sbuf  = (unsigned short*)(base + 32 * MB);  // 8MB bf16 scores
    unsigned short* WT    = (unsigned short*)(base + 40 * MB);  // 1.2MB

    // 1. casts (x -> bf16, weights -> transposed bf16)
    cast_all<<<2624, 256, 0, stream>>>(x, xb, Wlk, Wrk, Wlv, Wrv, Wout, W1, W2, WT);
    // 2. projections + head-major scatter
    proj_mfma<<<dim3(16, 64), 256, 0, stream>>>(xb, WT, projT);
    // 3. scores via MFMA -> S (bf16), occupancy-split
    scores_mfma<<<512, 256, 0, stream>>>(lkT, rkT, Sbuf);
    // 4. softmax + aggregation -> obuf (bf16)
    softmax_agg<<<1024, 256, 0, stream>>>(Sbuf, lvT, rvT, obufb);
    // 5. hb = LN(x + obuf @ W_out) (bf16)
    gemm_ln1<<<512, 256, 0, stream>>>(obufb, WT + 262144, x, g1, be1, hb);
    // 6. midb = relu(hb @ W1 + b1) (bf16)
    gemm_ffn1<<<dim3(8, 64), 256, 0, stream>>>(hb, WT + 327680, b1, midb);
    // 7. out = LN(hb + midb @ W2 + b2) -> fp32 d_out
    gemm_ln2<<<512, 256, 0, stream>>>(midb, WT + 458752, b2, hb, g2, be2, (float*)d_out);
}

// Round 14
// 192.122 us; speedup vs baseline: 1.0036x; 1.0036x over previous
//
#include <hip/hip_runtime.h>

// B=2, N=64, D=256, H=8, DK=32.  ROWS = B*N*N = 8192.
#define ROWS 8192
#define DIM  256

typedef short short8 __attribute__((ext_vector_type(8)));
typedef float f4     __attribute__((ext_vector_type(4)));
typedef float f2     __attribute__((ext_vector_type(2)));

__device__ __forceinline__ float bf2f(unsigned int u16) {
    union { unsigned int i; float f; } v;
    v.i = (u16 & 0xffffu) << 16;
    return v.f;
}
__device__ __forceinline__ float bf2f_hi(unsigned int u) {   // high bf16 of dword
    union { unsigned int i; float f; } v;
    v.i = u & 0xffff0000u;
    return v.f;
}
__device__ __forceinline__ unsigned short f2bf(float f) {
    union { float f; unsigned int u; } v; v.f = f;
    unsigned int r = v.u + 0x7fffu + ((v.u >> 16) & 1u);   // RNE
    return (unsigned short)(r >> 16);
}

// ---------------------------------------------------------------------------
// Merged casts. Blocks [0,2048): x(8192x256 fp32)->xb bf16.
// Blocks [2048,2624): weights -> WT[n][k] bf16 packed.
//   w0..w4 at w*65536 ; W1(256x512)->512x256 @327680 ; W2(512x256)->256x512 @458752
// ---------------------------------------------------------------------------
__global__ __launch_bounds__(256)
void cast_all(const float* __restrict__ x, unsigned short* __restrict__ xb,
              const float* __restrict__ w0, const float* __restrict__ w1,
              const float* __restrict__ w2, const float* __restrict__ w3,
              const float* __restrict__ w4, const float* __restrict__ w5,
              const float* __restrict__ w6, unsigned short* __restrict__ wt)
{
    if (blockIdx.x < 2048) {
        const size_t i = ((size_t)blockIdx.x * 256 + threadIdx.x) * 4;
        float4 v = *(const float4*)(x + i);
        uint2 p;
        p.x = f2bf(v.x) | ((unsigned int)f2bf(v.y) << 16);
        p.y = f2bf(v.z) | ((unsigned int)f2bf(v.w) << 16);
        *(uint2*)(xb + i) = p;
        return;
    }
    __shared__ float t[32][33];
    int id = blockIdx.x - 2048;
    const float* src; int K, N, Ntiles; size_t doff;
    if (id < 320) {
        int w = id >> 6; id &= 63; K = 256; N = 256; Ntiles = 8;
        doff = (size_t)w * 65536;
        src = (w == 0) ? w0 : (w == 1) ? w1 : (w == 2) ? w2 : (w == 3) ? w3 : w4;
    } else if (id < 448) {
        id -= 320; K = 256; N = 512; Ntiles = 16; doff = 327680; src = w5;
    } else {
        id -= 448; K = 512; N = 256; Ntiles = 8;  doff = 458752; src = w6;
    }
    const int tk = id / Ntiles, tn = id % Ntiles;
    const int k0 = tk * 32, n0 = tn * 32;
    const int c = threadIdx.x & 31, r8 = threadIdx.x >> 5;
    for (int rr = r8; rr < 32; rr += 8)
        t[rr][c] = src[(size_t)(k0 + rr) * N + n0 + c];
    __syncthreads();
    for (int rr = r8; rr < 32; rr += 8)
        wt[doff + (size_t)(n0 + rr) * K + k0 + c] = f2bf(t[c][rr]);
}

// ---------------------------------------------------------------------------
// Projection MFMA GEMM with head-major scatter epilogue (all-bf16 projT).
//   wsel 0 (lk): dst[b][h][x=i][a=j][d]   wsel 1 (rk): dst[b][h][a=i][y=j][d]
//   wsel 2 (lv): dst[b][h][x=i][a=j][d]   wsel 3 (rv): dst[b][h][y=j][a=i][d]
// grid = (16, 64)
// ---------------------------------------------------------------------------
__global__ __launch_bounds__(256)
void proj_mfma(const unsigned short* __restrict__ A, const unsigned short* __restrict__ WT,
               unsigned short* __restrict__ projT)
{
    const int lane = threadIdx.x & 63, wave = threadIdx.x >> 6;
    const int wsel = blockIdx.x >> 2;
    const int col0 = (blockIdx.x & 3) * 64;
    const int m0 = blockIdx.y * 128 + wave * 32;
    const int lm = lane & 15, lk8 = (lane >> 4) * 8;
    const unsigned short* W = WT + (size_t)wsel * 65536;
    unsigned short* dst = projT + (size_t)wsel * 2097152;

    f4 acc[2][4];
    #pragma unroll
    for (int i = 0; i < 2; ++i)
        #pragma unroll
        for (int j = 0; j < 4; ++j) acc[i][j] = (f4){0.f, 0.f, 0.f, 0.f};

    #pragma unroll 2
    for (int kc = 0; kc < 256; kc += 32) {
        short8 af[2], bf[4];
        #pragma unroll
        for (int i = 0; i < 2; ++i)
            af[i] = *(const short8*)(A + (size_t)(m0 + i * 16 + lm) * 256 + kc + lk8);
        #pragma unroll
        for (int j = 0; j < 4; ++j)
            bf[j] = *(const short8*)(W + (size_t)(col0 + j * 16 + lm) * 256 + kc + lk8);
        #pragma unroll
        for (int i = 0; i < 2; ++i)
            #pragma unroll
            for (int j = 0; j < 4; ++j)
                acc[i][j] = __builtin_amdgcn_mfma_f32_16x16x32_bf16(af[i], bf[j], acc[i][j], 0, 0, 0);
    }

    const int rbase = (lane >> 4) * 4;
    const int swap = (wsel == 3);
    #pragma unroll
    for (int i = 0; i < 2; ++i)
        #pragma unroll
        for (int j = 0; j < 4; ++j) {
            const int c = col0 + j * 16 + lm;
            const int h = c >> 5, d = c & 31;
            #pragma unroll
            for (int r = 0; r < 4; ++r) {
                const int m = m0 + i * 16 + rbase + r;
                const int b = m >> 12, ii = (m >> 6) & 63, jj = m & 63;
                const int p = swap ? jj : ii;
                const int q = swap ? ii : jj;
                const size_t idx = ((((size_t)b * 8 + h) * 64 + p) * 64 + q) * 32 + d;
                dst[idx] = f2bf(acc[i][j][r]);
            }
        }
}

// ---------------------------------------------------------------------------
// Scores via MFMA, occupancy-split: each (b,h,a) slice is TWO wave-tasks
// (mt-halves).  grid = 512 (16 bh x 32), 256 thr.  S[b][h][x][a][y] bf16.
// ---------------------------------------------------------------------------
__global__ __launch_bounds__(256)
void scores_mfma(const unsigned short* __restrict__ lkT, const unsigned short* __restrict__ rkT,
                 unsigned short* __restrict__ S)
{
    const int lane = threadIdx.x & 63, wave = threadIdx.x >> 6;
    const int bi = blockIdx.x;
    const size_t bh = bi >> 5;
    const int s = (bi & 31) * 4 + wave;
    const int a = s >> 1, half = s & 1;
    const int lm = lane & 15, lk8 = (lane >> 4) * 8;

    short8 af[2], bf[4];
    #pragma unroll
    for (int t = 0; t < 2; ++t)
        af[t] = *(const short8*)(lkT + ((bh * 64 + ((half * 2 + t) * 16 + lm)) * 64 + a) * 32 + lk8);
    #pragma unroll
    for (int t = 0; t < 4; ++t)
        bf[t] = *(const short8*)(rkT + ((bh * 64 + a) * 64 + (t * 16 + lm)) * 32 + lk8);

    const int rbase = (lane >> 4) * 4;
    unsigned short* Sb = S + bh * 262144 + a * 64;   // + x*4096 + y
    #pragma unroll
    for (int mt = 0; mt < 2; ++mt)
        #pragma unroll
        for (int nt = 0; nt < 4; ++nt) {
            f4 acc = (f4){0.f, 0.f, 0.f, 0.f};
            acc = __builtin_amdgcn_mfma_f32_16x16x32_bf16(af[mt], bf[nt], acc, 0, 0, 0);
            #pragma unroll
            for (int r = 0; r < 4; ++r) {
                const int xx = (half * 2 + mt) * 16 + rbase + r;
                const int yy = nt * 16 + lm;
                Sb[(size_t)xx * 4096 + yy] = f2bf(acc[r] * 0.17677669529663687f);
            }
        }
}

// ---------------------------------------------------------------------------
// Softmax over a + aggregation, block per (b,h,x), 256 thr.
// Aggregation inner loop on float2 ext-vectors -> v_pk_mul_f32/v_pk_fma_f32
// (2 fp32 ops/instr): the scalar form was VALU-issue-bound at ~27us chipwide
// (2.15e9 lane-ops / 78.6T fma/s).  rv stays bf16 (fp32 rv stream = +7us, r11).
// obuf[(b*64+x)*64+y][h*32+d] bf16.  grid = 1024.
// ---------------------------------------------------------------------------
__global__ __launch_bounds__(256)
void softmax_agg(const unsigned short* __restrict__ S, const unsigned short* __restrict__ lvT,
                 const unsigned short* __restrict__ rvT, unsigned short* __restrict__ obuf)
{
    __shared__ float att[64][64];           // [a][y]
    __shared__ float lvL[64][32];
    __shared__ float smx[4][64], ssm[4][64], invL[64];
    const int bi = blockIdx.x;
    const int b = bi >> 9, h = (bi >> 6) & 7, x = bi & 63;
    const size_t bh = (size_t)b * 8 + h;
    const int tid = threadIdx.x;

    {   // load S[x] slice (8KB bf16, contiguous) -> att f32 ; stage lv -> f32
        const int a = tid >> 2, yo = (tid & 3) * 16;
        const unsigned short* Sp = S + (bh * 64 + x) * 4096 + a * 64 + yo;
        uint4 p0 = *(const uint4*)(Sp);
        uint4 p1 = *(const uint4*)(Sp + 8);
        att[a][yo +  0] = bf2f(p0.x); att[a][yo +  1] = bf2f_hi(p0.x);
        att[a][yo +  2] = bf2f(p0.y); att[a][yo +  3] = bf2f_hi(p0.y);
        att[a][yo +  4] = bf2f(p0.z); att[a][yo +  5] = bf2f_hi(p0.z);
        att[a][yo +  6] = bf2f(p0.w); att[a][yo +  7] = bf2f_hi(p0.w);
        att[a][yo +  8] = bf2f(p1.x); att[a][yo +  9] = bf2f_hi(p1.x);
        att[a][yo + 10] = bf2f(p1.y); att[a][yo + 11] = bf2f_hi(p1.y);
        att[a][yo + 12] = bf2f(p1.z); att[a][yo + 13] = bf2f_hi(p1.z);
        att[a][yo + 14] = bf2f(p1.w); att[a][yo + 15] = bf2f_hi(p1.w);
        const int d0 = (tid & 3) * 8;
        uint4 q = *(const uint4*)(lvT + ((bh * 64 + x) * 64 + a) * 32 + d0);
        lvL[a][d0 + 0] = bf2f(q.x); lvL[a][d0 + 1] = bf2f_hi(q.x);
        lvL[a][d0 + 2] = bf2f(q.y); lvL[a][d0 + 3] = bf2f_hi(q.y);
        lvL[a][d0 + 4] = bf2f(q.z); lvL[a][d0 + 5] = bf2f_hi(q.z);
        lvL[a][d0 + 6] = bf2f(q.w); lvL[a][d0 + 7] = bf2f_hi(q.w);
    }
    __syncthreads();

    {   // per-slice max over a
        const int y = tid & 63, az = tid >> 6;
        float mx = -1e30f;
        for (int a = az; a < 64; a += 4) mx = fmaxf(mx, att[a][y]);
        smx[az][y] = mx;
    }
    __syncthreads();

    {   // exp + partial sums
        const int y = tid & 63, az = tid >> 6;
        const float mx = fmaxf(fmaxf(smx[0][y], smx[1][y]), fmaxf(smx[2][y], smx[3][y]));
        float s = 0.f;
        for (int a = az; a < 64; a += 4) {
            float e = __expf(att[a][y] - mx);
            att[a][y] = e;
            s += e;
        }
        ssm[az][y] = s;
    }
    __syncthreads();
    if (tid < 64)
        invL[tid] = 1.f / (ssm[0][tid] + ssm[1][tid] + ssm[2][tid] + ssm[3][tid]);
    __syncthreads();

    {   // aggregation: thread = (y = tid>>2, dq = tid&3), 8 d's, packed fp32
        const int y = tid >> 2, d0 = (tid & 3) * 8;
        f2 o0 = (f2){0.f, 0.f}, o1 = (f2){0.f, 0.f};
        f2 o2 = (f2){0.f, 0.f}, o3 = (f2){0.f, 0.f};
        const unsigned short* rvr = rvT + (bh * 64 + y) * 2048 + d0;
        #pragma unroll 8
        for (int a = 0; a < 64; ++a) {
            const float w = att[a][y];
            const f2 w2 = (f2){w, w};
            float4 lvA = *(const float4*)&lvL[a][d0];
            float4 lvB = *(const float4*)&lvL[a][d0 + 4];
            uint4 rv4 = *(const uint4*)(rvr + (size_t)a * 32);
            f2 rv0 = (f2){bf2f(rv4.x), bf2f_hi(rv4.x)};
            f2 rv1 = (f2){bf2f(rv4.y), bf2f_hi(rv4.y)};
            f2 rv2 = (f2){bf2f(rv4.z), bf2f_hi(rv4.z)};
            f2 rv3 = (f2){bf2f(rv4.w), bf2f_hi(rv4.w)};
            o0 = __builtin_elementwise_fma(w2 * (f2){lvA.x, lvA.y}, rv0, o0);
            o1 = __builtin_elementwise_fma(w2 * (f2){lvA.z, lvA.w}, rv1, o1);
            o2 = __builtin_elementwise_fma(w2 * (f2){lvB.x, lvB.y}, rv2, o2);
            o3 = __builtin_elementwise_fma(w2 * (f2){lvB.z, lvB.w}, rv3, o3);
        }
        const float inv = invL[y];
        uint4 pk;
        pk.x = f2bf(o0.x * inv) | ((unsigned int)f2bf(o0.y * inv) << 16);
        pk.y = f2bf(o1.x * inv) | ((unsigned int)f2bf(o1.y * inv) << 16);
        pk.z = f2bf(o2.x * inv) | ((unsigned int)f2bf(o2.y * inv) << 16);
        pk.w = f2bf(o3.x * inv) | ((unsigned int)f2bf(o3.y * inv) << 16);
        *(uint4*)(obuf + (((size_t)b * 64 + x) * 64 + y) * 256 + h * 32 + d0) = pk;
    }
}

// ---------------------------------------------------------------------------
// Fused GEMM + residual + LayerNorm (out-proj + LN1).
// tile: 16 rows x 256 cols; 4 waves, wave w covers cols w*64..+63.
// grid = 512, 256 thr.  resid fp32 (x), out bf16 (hb).
// ---------------------------------------------------------------------------
__global__ __launch_bounds__(256)
void gemm_ln1(const unsigned short* __restrict__ A, const unsigned short* __restrict__ WT,
              const float* __restrict__ resid,
              const float* __restrict__ gamma, const float* __restrict__ beta,
              unsigned short* __restrict__ out)
{
    constexpr int K = 256;
    __shared__ float ps[16][4], pq[16][4];
    const int lane = threadIdx.x & 63, wave = threadIdx.x >> 6;
    const int m0 = blockIdx.x * 16;
    const int col0 = wave * 64;
    const int lm = lane & 15, lk8 = (lane >> 4) * 8;

    f4 acc[4];
    #pragma unroll
    for (int j = 0; j < 4; ++j) acc[j] = (f4){0.f, 0.f, 0.f, 0.f};

    #pragma unroll 2
    for (int kc = 0; kc < K; kc += 32) {
        short8 af = *(const short8*)(A + (size_t)(m0 + lm) * K + kc + lk8);
        #pragma unroll
        for (int j = 0; j < 4; ++j) {
            short8 bf = *(const short8*)(WT + (size_t)(col0 + j * 16 + lm) * K + kc + lk8);
            acc[j] = __builtin_amdgcn_mfma_f32_16x16x32_bf16(af, bf, acc[j], 0, 0, 0);
        }
    }

    const int rbase = (lane >> 4) * 4;
    float v[4][4];
    float s[4] = {0.f, 0.f, 0.f, 0.f}, q[4] = {0.f, 0.f, 0.f, 0.f};
    #pragma unroll
    for (int j = 0; j < 4; ++j) {
        const int n = col0 + j * 16 + lm;
        #pragma unroll
        for (int r = 0; r < 4; ++r) {
            const int m = m0 + rbase + r;
            float t = acc[j][r] + resid[(size_t)m * 256 + n];
            v[j][r] = t;
            s[r] += t;
            q[r] = fmaf(t, t, q[r]);
        }
    }
    #pragma unroll
    for (int off = 1; off < 16; off <<= 1) {
        #pragma unroll
        for (int r = 0; r < 4; ++r) {
            s[r] += __shfl_xor(s[r], off);
            q[r] += __shfl_xor(q[r], off);
        }
    }
    if (lm == 0) {
        #pragma unroll
        for (int r = 0; r < 4; ++r) {
            ps[rbase + r][wave] = s[r];
            pq[rbase + r][wave] = q[r];
        }
    }
    __syncthreads();
    #pragma unroll
    for (int r = 0; r < 4; ++r) {
        const int lr = rbase + r;
        const float Sm = ps[lr][0] + ps[lr][1] + ps[lr][2] + ps[lr][3];
        const float Qm = pq[lr][0] + pq[lr][1] + pq[lr][2] + pq[lr][3];
        const float mu = Sm * (1.f / 256.f);
        const float ri = rsqrtf(Qm * (1.f / 256.f) - mu * mu + 1e-5f);
        const int m = m0 + lr;
        #pragma unroll
        for (int j = 0; j < 4; ++j) {
            const int n = col0 + j * 16 + lm;
            out[(size_t)m * 256 + n] = f2bf((v[j][r] - mu) * ri * gamma[n] + beta[n]);
        }
    }
}

// ---------------------------------------------------------------------------
// FFN1: out = relu( A(8192x256 bf16) @ WT(512x256)^T + bias ), bf16 out.
// tile 128x64 (wave = 32 rows x 64 cols), grid = (8, 64).
// ---------------------------------------------------------------------------
__global__ __launch_bounds__(256)
void gemm_ffn1(const unsigned short* __restrict__ A, const unsigned short* __restrict__ WT,
               const float* __restrict__ bias, unsigned short* __restrict__ outB)
{
    constexpr int K = 256, N = 512;
    const int lane = threadIdx.x & 63, wave = threadIdx.x >> 6;
    const int m0 = blockIdx.y * 128 + wave * 32;
    const int col0 = blockIdx.x * 64;
    const int lm = lane & 15, lk8 = (lane >> 4) * 8;

    f4 acc[2][4];
    #pragma unroll
    for (int i = 0; i < 2; ++i)
        #pragma unroll
        for (int j = 0; j < 4; ++j) acc[i][j] = (f4){0.f, 0.f, 0.f, 0.f};

    #pragma unroll 2
    for (int kc = 0; kc < K; kc += 32) {
        short8 af[2], bf[4];
        #pragma unroll
        for (int i = 0; i < 2; ++i)
            af[i] = *(const short8*)(A + (size_t)(m0 + i * 16 + lm) * K + kc + lk8);
        #pragma unroll
        for (int j = 0; j < 4; ++j)
            bf[j] = *(const short8*)(WT + (size_t)(col0 + j * 16 + lm) * K + kc + lk8);
        #pragma unroll
        for (int i = 0; i < 2; ++i)
            #pragma unroll
            for (int j = 0; j < 4; ++j)
                acc[i][j] = __builtin_amdgcn_mfma_f32_16x16x32_bf16(af[i], bf[j], acc[i][j], 0, 0, 0);
    }

    const int rbase = (lane >> 4) * 4;
    #pragma unroll
    for (int i = 0; i < 2; ++i)
        #pragma unroll
        for (int j = 0; j < 4; ++j) {
            const int n = col0 + j * 16 + lm;
            const float bb = bias[n];
            #pragma unroll
            for (int r = 0; r < 4; ++r) {
                const int m = m0 + i * 16 + rbase + r;
                outB[(size_t)m * N + n] = f2bf(fmaxf(acc[i][j][r] + bb, 0.f));
            }
        }
}

// ---------------------------------------------------------------------------
// FFN2 + residual(bf16 hb) + LN2 -> fp32 out.  K=512 compile-time.
// tile: 16 rows x 256 cols; 4 waves.  grid = 512, 256 thr.
// ---------------------------------------------------------------------------
__global__ __launch_bounds__(256)
void gemm_ln2(const unsigned short* __restrict__ A, const unsigned short* __restrict__ WT,
              const float* __restrict__ bias, const unsigned short* __restrict__ resid,
              const float* __restrict__ gamma, const float* __restrict__ beta,
              float* __restrict__ out)
{
    constexpr int K = 512;
    __shared__ float ps[16][4], pq[16][4];
    const int lane = threadIdx.x & 63, wave = threadIdx.x >> 6;
    const int m0 = blockIdx.x * 16;
    const int col0 = wave * 64;
    const int lm = lane & 15, lk8 = (lane >> 4) * 8;

    f4 acc[4];
    #pragma unroll
    for (int j = 0; j < 4; ++j) acc[j] = (f4){0.f, 0.f, 0.f, 0.f};

    #pragma unroll 2
    for (int kc = 0; kc < K; kc += 32) {
        short8 af = *(const short8*)(A + (size_t)(m0 + lm) * K + kc + lk8);
        #pragma unroll
        for (int j = 0; j < 4; ++j) {
            short8 bf = *(const short8*)(WT + (size_t)(col0 + j * 16 + lm) * K + kc + lk8);
            acc[j] = __builtin_amdgcn_mfma_f32_16x16x32_bf16(af, bf, acc[j], 0, 0, 0);
        }
    }

    const int rbase = (lane >> 4) * 4;
    float v[4][4];
    float s[4] = {0.f, 0.f, 0.f, 0.f}, q[4] = {0.f, 0.f, 0.f, 0.f};
    #pragma unroll
    for (int j = 0; j < 4; ++j) {
        const int n = col0 + j * 16 + lm;
        const float bb = bias[n];
        #pragma unroll
        for (int r = 0; r < 4; ++r) {
            const int m = m0 + rbase + r;
            float t = acc[j][r] + bb + bf2f(resid[(size_t)m * 256 + n]);
            v[j][r] = t;
            s[r] += t;
            q[r] = fmaf(t, t, q[r]);
        }
    }
    #pragma unroll
    for (int off = 1; off < 16; off <<= 1) {
        #pragma unroll
        for (int r = 0; r < 4; ++r) {
            s[r] += __shfl_xor(s[r], off);
            q[r] += __shfl_xor(q[r], off);
        }
    }
    if (lm == 0) {
        #pragma unroll
        for (int r = 0; r < 4; ++r) {
            ps[rbase + r][wave] = s[r];
            pq[rbase + r][wave] = q[r];
        }
    }
    __syncthreads();
    #pragma unroll
    for (int r = 0; r < 4; ++r) {
        const int lr = rbase + r;
        const float Sm = ps[lr][0] + ps[lr][1] + ps[lr][2] + ps[lr][3];
        const float Qm = pq[lr][0] + pq[lr][1] + pq[lr][2] + pq[lr][3];
        const float mu = Sm * (1.f / 256.f);
        const float ri = rsqrtf(Qm * (1.f / 256.f) - mu * mu + 1e-5f);
        const int m = m0 + lr;
        #pragma unroll
        for (int j = 0; j < 4; ++j) {
            const int n = col0 + j * 16 + lm;
            out[(size_t)m * 256 + n] = (v[j][r] - mu) * ri * gamma[n] + beta[n];
        }
    }
}

// ---------------------------------------------------------------------------
extern "C" void kernel_launch(void* const* d_in, const int* in_sizes, int n_in,
                              void* d_out, int out_size, void* d_ws, size_t ws_size,
                              hipStream_t stream)
{
    const float* x    = (const float*)d_in[0];
    const float* Wlk  = (const float*)d_in[1];
    const float* Wrk  = (const float*)d_in[2];
    const float* Wlv  = (const float*)d_in[3];
    const float* Wrv  = (const float*)d_in[4];
    const float* Wout = (const float*)d_in[5];
    const float* g1   = (const float*)d_in[6];
    const float* be1  = (const float*)d_in[7];
    const float* W1   = (const float*)d_in[8];
    const float* b1   = (const float*)d_in[9];
    const float* W2   = (const float*)d_in[10];
    const float* b2   = (const float*)d_in[11];
    const float* g2   = (const float*)d_in[12];
    const float* be2  = (const float*)d_in[13];

    char* base = (char*)d_ws;
    const size_t MB = 1ull << 20;
    unsigned short* xb    = (unsigned short*)(base + 0);        // 4MB; reused as obuf
    unsigned short* obufb = (unsigned short*)(base + 0);
    unsigned short* projT = (unsigned short*)(base + 4 * MB);   // lkT,rkT,lvT,rvT 4x4MB
    unsigned short* lkT   = projT;
    unsigned short* rkT   = projT + 2097152;
    unsigned short* lvT   = projT + 2 * 2097152;
    unsigned short* rvT   = projT + 3 * 2097152;
    unsigned short* hb    = (unsigned short*)(base + 20 * MB);  // 4MB bf16 h
    unsigned short* midb  = (unsigned short*)(base + 24 * MB);  // 8MB
    unsigned short* Sbuf  = (unsigned short*)(base + 32 * MB);  // 8MB bf16 scores
    unsigned short* WT    = (unsigned short*)(base + 40 * MB);  // 1.2MB

    // 1. casts (x -> bf16, weights -> transposed bf16)
    cast_all<<<2624, 256, 0, stream>>>(x, xb, Wlk, Wrk, Wlv, Wrv, Wout, W1, W2, WT);
    // 2. projections + head-major scatter
    proj_mfma<<<dim3(16, 64), 256, 0, stream>>>(xb, WT, projT);
    // 3. scores via MFMA -> S (bf16), occupancy-split
    scores_mfma<<<512, 256, 0, stream>>>(lkT, rkT, Sbuf);
    // 4. softmax + aggregation (packed fp32) -> obuf (bf16)
    softmax_agg<<<1024, 256, 0, stream>>>(Sbuf, lvT, rvT, obufb);
    // 5. hb = LN(x + obuf @ W_out) (bf16)
    gemm_ln1<<<512, 256, 0, stream>>>(obufb, WT + 262144, x, g1, be1, hb);
    // 6. midb = relu(hb @ W1 + b1) (bf16)
    gemm_ffn1<<<dim3(8, 64), 256, 0, stream>>>(hb, WT + 327680, b1, midb);
    // 7. out = LN(hb + midb @ W2 + b2) -> fp32 d_out
    gemm_ln2<<<512, 256, 0, stream>>>(midb, WT + 458752, b2, hb, g2, be2, (float*)d_out);
}

// Round 15
// 189.037 us; speedup vs baseline: 1.0200x; 1.0163x over previous
//
#include <hip/hip_runtime.h>

// B=2, N=64, D=256, H=8, DK=32.  ROWS = B*N*N = 8192.
// Round 15 = exact round-10 configuration (empirical best, 187.2us):
// test-retest to separate real config advantage from run-to-run noise.
#define ROWS 8192
#define DIM  256

typedef short short8 __attribute__((ext_vector_type(8)));
typedef float f4     __attribute__((ext_vector_type(4)));

__device__ __forceinline__ float bf2f(unsigned int u16) {
    union { unsigned int i; float f; } v;
    v.i = (u16 & 0xffffu) << 16;
    return v.f;
}
__device__ __forceinline__ unsigned short f2bf(float f) {
    union { float f; unsigned int u; } v; v.f = f;
    unsigned int r = v.u + 0x7fffu + ((v.u >> 16) & 1u);   // RNE
    return (unsigned short)(r >> 16);
}

// ---------------------------------------------------------------------------
// Merged casts. Blocks [0,2048): x(8192x256 fp32)->xb bf16.
// Blocks [2048,2624): weights -> WT[n][k] bf16 packed.
//   w0..w4 at w*65536 ; W1(256x512)->512x256 @327680 ; W2(512x256)->256x512 @458752
// ---------------------------------------------------------------------------
__global__ __launch_bounds__(256)
void cast_all(const float* __restrict__ x, unsigned short* __restrict__ xb,
              const float* __restrict__ w0, const float* __restrict__ w1,
              const float* __restrict__ w2, const float* __restrict__ w3,
              const float* __restrict__ w4, const float* __restrict__ w5,
              const float* __restrict__ w6, unsigned short* __restrict__ wt)
{
    if (blockIdx.x < 2048) {
        const size_t i = ((size_t)blockIdx.x * 256 + threadIdx.x) * 4;
        float4 v = *(const float4*)(x + i);
        uint2 p;
        p.x = f2bf(v.x) | ((unsigned int)f2bf(v.y) << 16);
        p.y = f2bf(v.z) | ((unsigned int)f2bf(v.w) << 16);
        *(uint2*)(xb + i) = p;
        return;
    }
    __shared__ float t[32][33];
    int id = blockIdx.x - 2048;
    const float* src; int K, N, Ntiles; size_t doff;
    if (id < 320) {
        int w = id >> 6; id &= 63; K = 256; N = 256; Ntiles = 8;
        doff = (size_t)w * 65536;
        src = (w == 0) ? w0 : (w == 1) ? w1 : (w == 2) ? w2 : (w == 3) ? w3 : w4;
    } else if (id < 448) {
        id -= 320; K = 256; N = 512; Ntiles = 16; doff = 327680; src = w5;
    } else {
        id -= 448; K = 512; N = 256; Ntiles = 8;  doff = 458752; src = w6;
    }
    const int tk = id / Ntiles, tn = id % Ntiles;
    const int k0 = tk * 32, n0 = tn * 32;
    const int c = threadIdx.x & 31, r8 = threadIdx.x >> 5;
    for (int rr = r8; rr < 32; rr += 8)
        t[rr][c] = src[(size_t)(k0 + rr) * N + n0 + c];
    __syncthreads();
    for (int rr = r8; rr < 32; rr += 8)
        wt[doff + (size_t)(n0 + rr) * K + k0 + c] = f2bf(t[c][rr]);
}

// ---------------------------------------------------------------------------
// Projection MFMA GEMM with head-major scatter epilogue.
//   wsel 0 (lk): dst[b][h][x=i][a=j][d]   wsel 1 (rk): dst[b][h][a=i][y=j][d]
//   wsel 2 (lv): dst[b][h][x=i][a=j][d]   wsel 3 (rv): dst[b][h][y=j][a=i][d]
// grid = (16, 64)
// ---------------------------------------------------------------------------
__global__ __launch_bounds__(256)
void proj_mfma(const unsigned short* __restrict__ A, const unsigned short* __restrict__ WT,
               unsigned short* __restrict__ projT)
{
    const int lane = threadIdx.x & 63, wave = threadIdx.x >> 6;
    const int wsel = blockIdx.x >> 2;
    const int col0 = (blockIdx.x & 3) * 64;
    const int m0 = blockIdx.y * 128 + wave * 32;
    const int lm = lane & 15, lk8 = (lane >> 4) * 8;
    const unsigned short* W = WT + (size_t)wsel * 65536;
    unsigned short* dst = projT + (size_t)wsel * 2097152;

    f4 acc[2][4];
    #pragma unroll
    for (int i = 0; i < 2; ++i)
        #pragma unroll
        for (int j = 0; j < 4; ++j) acc[i][j] = (f4){0.f, 0.f, 0.f, 0.f};

    #pragma unroll 2
    for (int kc = 0; kc < 256; kc += 32) {
        short8 af[2], bf[4];
        #pragma unroll
        for (int i = 0; i < 2; ++i)
            af[i] = *(const short8*)(A + (size_t)(m0 + i * 16 + lm) * 256 + kc + lk8);
        #pragma unroll
        for (int j = 0; j < 4; ++j)
            bf[j] = *(const short8*)(W + (size_t)(col0 + j * 16 + lm) * 256 + kc + lk8);
        #pragma unroll
        for (int i = 0; i < 2; ++i)
            #pragma unroll
            for (int j = 0; j < 4; ++j)
                acc[i][j] = __builtin_amdgcn_mfma_f32_16x16x32_bf16(af[i], bf[j], acc[i][j], 0, 0, 0);
    }

    const int rbase = (lane >> 4) * 4;
    const int swap = (wsel == 3);
    #pragma unroll
    for (int i = 0; i < 2; ++i)
        #pragma unroll
        for (int j = 0; j < 4; ++j) {
            const int c = col0 + j * 16 + lm;
            const int h = c >> 5, d = c & 31;
            #pragma unroll
            for (int r = 0; r < 4; ++r) {
                const int m = m0 + i * 16 + rbase + r;
                const int b = m >> 12, ii = (m >> 6) & 63, jj = m & 63;
                const int p = swap ? jj : ii;
                const int q = swap ? ii : jj;
                const size_t idx = ((((size_t)b * 8 + h) * 64 + p) * 64 + q) * 32 + d;
                dst[idx] = f2bf(acc[i][j][r]);
            }
        }
}

// ---------------------------------------------------------------------------
// Scores via MFMA: per (b,h), wave w handles a = a0 + w.
//   S_a[x,y] = sum_d lk[x,a,d]*rk[a,y,d] / sqrt(32), stored bf16 as
//   S[b][h][x][a][y].  grid = 256 (b,h,a/4), 256 thr.
// ---------------------------------------------------------------------------
__global__ __launch_bounds__(256)
void scores_mfma(const unsigned short* __restrict__ lkT, const unsigned short* __restrict__ rkT,
                 unsigned short* __restrict__ S)
{
    const int lane = threadIdx.x & 63, wave = threadIdx.x >> 6;
    const int bi = blockIdx.x;
    const int b = bi >> 7, h = (bi >> 4) & 7, a = (bi & 15) * 4 + wave;
    const size_t bh = (size_t)b * 8 + h;
    const int lm = lane & 15, lk8 = (lane >> 4) * 8;

    short8 af[4], bf[4];
    #pragma unroll
    for (int t = 0; t < 4; ++t) {
        af[t] = *(const short8*)(lkT + ((bh * 64 + (t * 16 + lm)) * 64 + a) * 32 + lk8);
        bf[t] = *(const short8*)(rkT + ((bh * 64 + a) * 64 + (t * 16 + lm)) * 32 + lk8);
    }
    const int rbase = (lane >> 4) * 4;
    unsigned short* Sb = S + bh * 262144 + a * 64;   // + x*4096 + y
    #pragma unroll
    for (int mt = 0; mt < 4; ++mt)
        #pragma unroll
        for (int nt = 0; nt < 4; ++nt) {
            f4 acc = (f4){0.f, 0.f, 0.f, 0.f};
            acc = __builtin_amdgcn_mfma_f32_16x16x32_bf16(af[mt], bf[nt], acc, 0, 0, 0);
            #pragma unroll
            for (int r = 0; r < 4; ++r) {
                const int xx = mt * 16 + rbase + r;
                const int yy = nt * 16 + lm;
                Sb[(size_t)xx * 4096 + yy] = f2bf(acc[r] * 0.17677669529663687f);
            }
        }
}

// ---------------------------------------------------------------------------
// Softmax over a + aggregation, block per (b,h,x), 256 thr.
// obuf[(b*64+x)*64+y][h*32+d] bf16.  grid = 1024.
// ---------------------------------------------------------------------------
__global__ __launch_bounds__(256)
void softmax_agg(const unsigned short* __restrict__ S, const unsigned short* __restrict__ lvT,
                 const unsigned short* __restrict__ rvT, unsigned short* __restrict__ obuf)
{
    __shared__ float att[64][64];           // [a][y]
    __shared__ float lvL[64][32];
    __shared__ float smx[4][64], ssm[4][64], invL[64];
    const int bi = blockIdx.x;
    const int b = bi >> 9, h = (bi >> 6) & 7, x = bi & 63;
    const size_t bh = (size_t)b * 8 + h;
    const int tid = threadIdx.x;

    {   // load S[x] slice (8KB bf16, contiguous) -> att f32 ; stage lv -> f32
        const int a = tid >> 2, yo = (tid & 3) * 16;
        const unsigned short* Sp = S + (bh * 64 + x) * 4096 + a * 64 + yo;
        uint4 p0 = *(const uint4*)(Sp);
        uint4 p1 = *(const uint4*)(Sp + 8);
        att[a][yo +  0] = bf2f(p0.x); att[a][yo +  1] = bf2f(p0.x >> 16);
        att[a][yo +  2] = bf2f(p0.y); att[a][yo +  3] = bf2f(p0.y >> 16);
        att[a][yo +  4] = bf2f(p0.z); att[a][yo +  5] = bf2f(p0.z >> 16);
        att[a][yo +  6] = bf2f(p0.w); att[a][yo +  7] = bf2f(p0.w >> 16);
        att[a][yo +  8] = bf2f(p1.x); att[a][yo +  9] = bf2f(p1.x >> 16);
        att[a][yo + 10] = bf2f(p1.y); att[a][yo + 11] = bf2f(p1.y >> 16);
        att[a][yo + 12] = bf2f(p1.z); att[a][yo + 13] = bf2f(p1.z >> 16);
        att[a][yo + 14] = bf2f(p1.w); att[a][yo + 15] = bf2f(p1.w >> 16);
        const int d0 = (tid & 3) * 8;
        uint4 q = *(const uint4*)(lvT + ((bh * 64 + x) * 64 + a) * 32 + d0);
        lvL[a][d0 + 0] = bf2f(q.x); lvL[a][d0 + 1] = bf2f(q.x >> 16);
        lvL[a][d0 + 2] = bf2f(q.y); lvL[a][d0 + 3] = bf2f(q.y >> 16);
        lvL[a][d0 + 4] = bf2f(q.z); lvL[a][d0 + 5] = bf2f(q.z >> 16);
        lvL[a][d0 + 6] = bf2f(q.w); lvL[a][d0 + 7] = bf2f(q.w >> 16);
    }
    __syncthreads();

    {   // per-slice max over a
        const int y = tid & 63, az = tid >> 6;
        float mx = -1e30f;
        for (int a = az; a < 64; a += 4) mx = fmaxf(mx, att[a][y]);
        smx[az][y] = mx;
    }
    __syncthreads();

    {   // exp + partial sums
        const int y = tid & 63, az = tid >> 6;
        const float mx = fmaxf(fmaxf(smx[0][y], smx[1][y]), fmaxf(smx[2][y], smx[3][y]));
        float s = 0.f;
        for (int a = az; a < 64; a += 4) {
            float e = __expf(att[a][y] - mx);
            att[a][y] = e;
            s += e;
        }
        ssm[az][y] = s;
    }
    __syncthreads();
    if (tid < 64)
        invL[tid] = 1.f / (ssm[0][tid] + ssm[1][tid] + ssm[2][tid] + ssm[3][tid]);
    __syncthreads();

    {   // aggregation; thread = (dp = d-pair, yb); y = yb + 16*it
        const int dp = tid & 15, yb = tid >> 4;
        #pragma unroll
        for (int it = 0; it < 4; ++it) {
            const int y = yb + it * 16;
            const unsigned short* rvr = rvT + (bh * 64 + y) * 2048 + dp * 2;
            float a0 = 0.f, a1 = 0.f;
            #pragma unroll 8
            for (int a = 0; a < 64; ++a) {
                unsigned int pk = *(const unsigned int*)(rvr + a * 32);
                float w = att[a][y];
                a0 = fmaf(w * lvL[a][2 * dp],     bf2f(pk),       a0);
                a1 = fmaf(w * lvL[a][2 * dp + 1], bf2f(pk >> 16), a1);
            }
            const float inv = invL[y];
            a0 *= inv; a1 *= inv;
            unsigned int st = f2bf(a0) | ((unsigned int)f2bf(a1) << 16);
            *(unsigned int*)(obuf + (((size_t)b * 64 + x) * 64 + y) * 256 + h * 32 + dp * 2) = st;
        }
    }
}

// ---------------------------------------------------------------------------
// FFN1: out = relu( A(8192x256 bf16) @ WT(512x256)^T + bias ), bf16 out.
// Compile-time K/N so the K-loop unrolls & pipelines.
// tile 128x64 (wave = 32 rows x 64 cols), grid = (8, 64).
// ---------------------------------------------------------------------------
__global__ __launch_bounds__(256)
void gemm_ffn1(const unsigned short* __restrict__ A, const unsigned short* __restrict__ WT,
               const float* __restrict__ bias, unsigned short* __restrict__ outB)
{
    constexpr int K = 256, N = 512;
    const int lane = threadIdx.x & 63, wave = threadIdx.x >> 6;
    const int m0 = blockIdx.y * 128 + wave * 32;
    const int col0 = blockIdx.x * 64;
    const int lm = lane & 15, lk8 = (lane >> 4) * 8;

    f4 acc[2][4];
    #pragma unroll
    for (int i = 0; i < 2; ++i)
        #pragma unroll
        for (int j = 0; j < 4; ++j) acc[i][j] = (f4){0.f, 0.f, 0.f, 0.f};

    #pragma unroll 2
    for (int kc = 0; kc < K; kc += 32) {
        short8 af[2], bf[4];
        #pragma unroll
        for (int i = 0; i < 2; ++i)
            af[i] = *(const short8*)(A + (size_t)(m0 + i * 16 + lm) * K + kc + lk8);
        #pragma unroll
        for (int j = 0; j < 4; ++j)
            bf[j] = *(const short8*)(WT + (size_t)(col0 + j * 16 + lm) * K + kc + lk8);
        #pragma unroll
        for (int i = 0; i < 2; ++i)
            #pragma unroll
            for (int j = 0; j < 4; ++j)
                acc[i][j] = __builtin_amdgcn_mfma_f32_16x16x32_bf16(af[i], bf[j], acc[i][j], 0, 0, 0);
    }

    const int rbase = (lane >> 4) * 4;
    #pragma unroll
    for (int i = 0; i < 2; ++i)
        #pragma unroll
        for (int j = 0; j < 4; ++j) {
            const int n = col0 + j * 16 + lm;
            const float bb = bias[n];
            #pragma unroll
            for (int r = 0; r < 4; ++r) {
                const int m = m0 + i * 16 + rbase + r;
                outB[(size_t)m * N + n] = f2bf(fmaxf(acc[i][j][r] + bb, 0.f));
            }
        }
}

// ---------------------------------------------------------------------------
// Fused GEMM + residual + LayerNorm, templated on K / residual dtype / out dtype.
// tile: 16 rows x 256 cols; 4 waves, wave w covers cols w*64..+63.
//   t = A @ WT^T [+ bias] + resid ;  out = LN(t) * gamma + beta
// grid = 512 (8192/16), 256 thr.
// ---------------------------------------------------------------------------
template<int K, bool RBF16, bool OBF16>
__global__ __launch_bounds__(256)
void gemm_ln_t(const unsigned short* __restrict__ A, const unsigned short* __restrict__ WT,
               const float* __restrict__ bias, const void* __restrict__ resid,
               const float* __restrict__ gamma, const float* __restrict__ beta,
               void* __restrict__ out)
{
    __shared__ float ps[16][4], pq[16][4];
    const int lane = threadIdx.x & 63, wave = threadIdx.x >> 6;
    const int m0 = blockIdx.x * 16;
    const int col0 = wave * 64;
    const int lm = lane & 15, lk8 = (lane >> 4) * 8;

    f4 acc[4];
    #pragma unroll
    for (int j = 0; j < 4; ++j) acc[j] = (f4){0.f, 0.f, 0.f, 0.f};

    #pragma unroll 2
    for (int kc = 0; kc < K; kc += 32) {
        short8 af = *(const short8*)(A + (size_t)(m0 + lm) * K + kc + lk8);
        #pragma unroll
        for (int j = 0; j < 4; ++j) {
            short8 bf = *(const short8*)(WT + (size_t)(col0 + j * 16 + lm) * K + kc + lk8);
            acc[j] = __builtin_amdgcn_mfma_f32_16x16x32_bf16(af, bf, acc[j], 0, 0, 0);
        }
    }

    const int rbase = (lane >> 4) * 4;
    float v[4][4];
    float s[4] = {0.f, 0.f, 0.f, 0.f}, q[4] = {0.f, 0.f, 0.f, 0.f};
    #pragma unroll
    for (int j = 0; j < 4; ++j) {
        const int n = col0 + j * 16 + lm;
        const float bb = bias ? bias[n] : 0.f;
        #pragma unroll
        for (int r = 0; r < 4; ++r) {
            const int m = m0 + rbase + r;
            const size_t idx = (size_t)m * 256 + n;
            const float rr = RBF16 ? bf2f(((const unsigned short*)resid)[idx])
                                   : ((const float*)resid)[idx];
            float t = acc[j][r] + bb + rr;
            v[j][r] = t;
            s[r] += t;
            q[r] = fmaf(t, t, q[r]);
        }
    }
    #pragma unroll
    for (int off = 1; off < 16; off <<= 1) {
        #pragma unroll
        for (int r = 0; r < 4; ++r) {
            s[r] += __shfl_xor(s[r], off);
            q[r] += __shfl_xor(q[r], off);
        }
    }
    if (lm == 0) {
        #pragma unroll
        for (int r = 0; r < 4; ++r) {
            ps[rbase + r][wave] = s[r];
            pq[rbase + r][wave] = q[r];
        }
    }
    __syncthreads();
    #pragma unroll
    for (int r = 0; r < 4; ++r) {
        const int lr = rbase + r;
        const float Sm = ps[lr][0] + ps[lr][1] + ps[lr][2] + ps[lr][3];
        const float Qm = pq[lr][0] + pq[lr][1] + pq[lr][2] + pq[lr][3];
        const float mu = Sm * (1.f / 256.f);
        const float ri = rsqrtf(Qm * (1.f / 256.f) - mu * mu + 1e-5f);
        const int m = m0 + lr;
        #pragma unroll
        for (int j = 0; j < 4; ++j) {
            const int n = col0 + j * 16 + lm;
            const size_t idx = (size_t)m * 256 + n;
            const float rv = (v[j][r] - mu) * ri * gamma[n] + beta[n];
            if (OBF16) ((unsigned short*)out)[idx] = f2bf(rv);
            else       ((float*)out)[idx] = rv;
        }
    }
}

// ---------------------------------------------------------------------------
extern "C" void kernel_launch(void* const* d_in, const int* in_sizes, int n_in,
                              void* d_out, int out_size, void* d_ws, size_t ws_size,
                              hipStream_t stream)
{
    const float* x    = (const float*)d_in[0];
    const float* Wlk  = (const float*)d_in[1];
    const float* Wrk  = (const float*)d_in[2];
    const float* Wlv  = (const float*)d_in[3];
    const float* Wrv  = (const float*)d_in[4];
    const float* Wout = (const float*)d_in[5];
    const float* g1   = (const float*)d_in[6];
    const float* be1  = (const float*)d_in[7];
    const float* W1   = (const float*)d_in[8];
    const float* b1   = (const float*)d_in[9];
    const float* W2   = (const float*)d_in[10];
    const float* b2   = (const float*)d_in[11];
    const float* g2   = (const float*)d_in[12];
    const float* be2  = (const float*)d_in[13];

    char* base = (char*)d_ws;
    const size_t MB = 1ull << 20;
    unsigned short* xb    = (unsigned short*)(base + 0);        // 4MB; reused as obuf
    unsigned short* obufb = (unsigned short*)(base + 0);
    unsigned short* projT = (unsigned short*)(base + 4 * MB);   // lkT,rkT,lvT,rvT 4x4MB
    unsigned short* lkT   = projT;
    unsigned short* rkT   = projT + 2097152;
    unsigned short* lvT   = projT + 2 * 2097152;
    unsigned short* rvT   = projT + 3 * 2097152;
    unsigned short* hb    = (unsigned short*)(base + 20 * MB);  // 4MB bf16 h
    unsigned short* midb  = (unsigned short*)(base + 24 * MB);  // 8MB
    unsigned short* Sbuf  = (unsigned short*)(base + 32 * MB);  // 8MB bf16 scores
    unsigned short* WT    = (unsigned short*)(base + 40 * MB);  // 1.2MB

    // 1. casts (x -> bf16, weights -> transposed bf16)
    cast_all<<<2624, 256, 0, stream>>>(x, xb, Wlk, Wrk, Wlv, Wrv, Wout, W1, W2, WT);
    // 2. projections + head-major scatter
    proj_mfma<<<dim3(16, 64), 256, 0, stream>>>(xb, WT, projT);
    // 3. scores via MFMA -> S (bf16)
    scores_mfma<<<256, 256, 0, stream>>>(lkT, rkT, Sbuf);
    // 4. softmax + aggregation -> obuf (bf16)
    softmax_agg<<<1024, 256, 0, stream>>>(Sbuf, lvT, rvT, obufb);
    // 5. hb = LN(x + obuf @ W_out) (bf16)
    gemm_ln_t<256, false, true><<<512, 256, 0, stream>>>(obufb, WT + 262144, nullptr, x, g1, be1, hb);
    // 6. midb = relu(hb @ W1 + b1) (bf16)
    gemm_ffn1<<<dim3(8, 64), 256, 0, stream>>>(hb, WT + 327680, b1, midb);
    // 7. out = LN(hb + midb @ W2 + b2) -> fp32 d_out
    gemm_ln_t<512, true, false><<<512, 256, 0, stream>>>(midb, WT + 458752, b2, hb, g2, be2, (float*)d_out);
}